// Round 5
// baseline (2354.649 us; speedup 1.0000x reference)
//
#include <hip/hip_runtime.h>
#include <math.h>

// Bidirectional 10-layer tanh RNN, T=512 B=64 H=100, + sigmoid head.
// Layers strictly sequential (bidir dependency). Per layer:
//   1) ingemm_kernel: z[dir][m][h] = In[m][:] . Wd[h][:] + bias  (dir-split GEMM)
//   2) scan_kernel:   128 blocks = 2 dirs x 64 batch independent chains
// Final: outproj_kernel (wave-per-row dot200 + sigmoid).
//
// R5: ingemm rewritten zero-waste. Old 64x64-tile version wasted 22% (N=200
// over 64-col tiles) + 4% (K=200 over 16-k chunks) -> 61 TF effective.
// New: per-dir N=100 tiles. Block = 320 thr (20x16), M-tile 128 (A-frag =
// 2 b128 at ty*4 and 64+ty*4 -> 2-way bank = free), N-tile 100 (tx*5, Bs in
// stride-10 groups -> b64+b64+b32, 2-way = free), K-chunk 20 (exact for both
// K=200 and K=100). 40 FMA vs 5 DS per k -> FMA-bound.
// scan_kernel: R4 version kept unchanged (4 waves, jj spread across waves,
// 28 b128/step, DPP quad-xor reduce, raw s_barrier + lgkmcnt-only drain).

#define T_LEN 512
#define BATCH 64
#define HID   100
#define M_TOT (T_LEN * BATCH)   // 32768

// ---------------- input GEMM (per-dir, zero-waste tiling) ----------------
// Grid: (M_TOT/128, 2). Block 320 thr: tx = tid%20 (5 cols), ty = tid/20
// (8 rows as two 4-row halves at ty*4 and 64+ty*4).
__global__ __launch_bounds__(320) void ingemm_kernel(
    const float* __restrict__ In, const float* __restrict__ W,
    const float* __restrict__ bih, const float* __restrict__ bhh,
    float* __restrict__ z, int K)
{
    __shared__ float As[20][132];   // [k][m], m padded 128->132
    __shared__ float Bs[20][200];   // [k][grp*10 + e], grp=n/5, e=n%5

    const int tid = threadIdx.x;        // 0..319
    const int tx  = tid % 20;           // n-group
    const int ty  = tid / 20;           // 0..15
    const int m0  = blockIdx.x * 128;
    const int dir = blockIdx.y;

    const float* Wd = W + (size_t)dir * HID * K;   // this dir's 100 x K rows

    // bias for the 5 columns this thread owns
    float bsum[5];
    #pragma unroll
    for (int j = 0; j < 5; ++j) {
        const int n = dir * HID + tx * 5 + j;
        bsum[j] = bih[n] + bhh[n];
    }

    float acc[8][5];
    #pragma unroll
    for (int i = 0; i < 8; ++i)
        #pragma unroll
        for (int j = 0; j < 5; ++j) acc[i][j] = 0.f;

    for (int k0 = 0; k0 < K; k0 += 20) {
        // ---- stage A: 128 rows x 20 k = 640 float4 units, exactly 2/thread
        #pragma unroll
        for (int rep = 0; rep < 2; ++rep) {
            const int idx = tid + rep * 320;      // 0..639
            const int row = idx / 5;              // 0..127
            const int c   = idx % 5;              // f4 index in k-chunk
            float4 v = *(const float4*)(In + (size_t)(m0 + row) * K + k0 + 4 * c);
            As[4*c+0][row] = v.x; As[4*c+1][row] = v.y;
            As[4*c+2][row] = v.z; As[4*c+3][row] = v.w;
        }
        // ---- stage B: 100 rows x 20 k = 500 float4 units
        #pragma unroll
        for (int rep = 0; rep < 2; ++rep) {
            const int idx = tid + rep * 320;      // 0..639, use < 500
            if (idx < 500) {
                const int n = idx / 5;            // 0..99
                const int c = idx % 5;
                float4 v = *(const float4*)(Wd + (size_t)n * K + k0 + 4 * c);
                const int col = (n / 5) * 10 + (n % 5);
                Bs[4*c+0][col] = v.x; Bs[4*c+1][col] = v.y;
                Bs[4*c+2][col] = v.z; Bs[4*c+3][col] = v.w;
            }
        }
        __syncthreads();

        #pragma unroll
        for (int kk = 0; kk < 20; ++kk) {
            // A-frag: two 2-way-free b128s (rows ty*4.. and 64+ty*4..)
            float4 alo = *(const float4*)&As[kk][ty * 4];
            float4 ahi = *(const float4*)&As[kk][64 + ty * 4];
            float a[8] = {alo.x, alo.y, alo.z, alo.w,
                          ahi.x, ahi.y, ahi.z, ahi.w};
            // B-frag: b64 + b64 + b32 at stride-10 group (2-way-free)
            float2 b01 = *(const float2*)&Bs[kk][tx * 10];
            float2 b23 = *(const float2*)&Bs[kk][tx * 10 + 2];
            float  b4  = Bs[kk][tx * 10 + 4];
            float b[5] = {b01.x, b01.y, b23.x, b23.y, b4};
            #pragma unroll
            for (int i = 0; i < 8; ++i)
                #pragma unroll
                for (int j = 0; j < 5; ++j)
                    acc[i][j] += a[i] * b[j];
        }
        __syncthreads();
    }

    // epilogue: z[dir][m][h], h = tx*5+j; rows ty*4+i and 64+ty*4+i
    float* zd = z + (size_t)dir * M_TOT * HID;
    #pragma unroll
    for (int i = 0; i < 8; ++i) {
        const int m = m0 + ((i < 4) ? (ty * 4 + i) : (64 + ty * 4 + (i - 4)));
        float* zr = zd + (size_t)m * HID + tx * 5;
        #pragma unroll
        for (int j = 0; j < 5; ++j)
            zr[j] = acc[i][j] + bsum[j];
    }
}

// DPP quad-perm xor helpers — guaranteed VALU lane exchange (no LDS).
// quad_perm ctrl = p0 | p1<<2 | p2<<4 | p3<<6.
// xor1: {1,0,3,2} = 0xB1 ; xor2: {2,3,0,1} = 0x4E.
__device__ __forceinline__ float dpp_qxor1(float x) {
    int i = __float_as_int(x);
    i = __builtin_amdgcn_update_dpp(0, i, 0xB1, 0xF, 0xF, false);
    return __int_as_float(i);
}
__device__ __forceinline__ float dpp_qxor2(float x) {
    int i = __float_as_int(x);
    i = __builtin_amdgcn_update_dpp(0, i, 0x4E, 0xF, 0xF, false);
    return __int_as_float(i);
}

// ---------------- recurrent scan (R4, unchanged) ----------------
// One block (256 threads, 4 waves) per (dir, batch) chain.
// Lane (wave w, lane l): ks = l&3 (k-slice), jj = w + 4*(l>>2) (row pair).
// Active jj < 50; quads are jj-uniform so DPP quads never mix active/inactive.
__global__ __launch_bounds__(256) void scan_kernel(
    const float* __restrict__ z,    // [2][M][HID]
    const float* __restrict__ Whh,  // [2][HID][HID] for this layer
    float* __restrict__ out)        // [M][200]
{
    const int dir = blockIdx.x >> 6;
    const int b   = blockIdx.x & 63;
    const int tid = threadIdx.x;        // 0..255
    const int w   = tid >> 6;           // wave 0..3
    const int lane= tid & 63;
    const int ks  = lane & 3;           // k-slice 0..3
    const int jslot = lane >> 2;        // 0..15
    const int jj  = w + 4 * jslot;      // 0..63, spread across waves
    const bool active = (jj < 50);
    const int jjc = active ? jj : 49;   // clamped for safe addressing
    const int kb  = 28 * ks;            // k-slice base (h padded to 128)
    const int jout = 2 * jjc + (ks & 1);        // row this lane finalizes
    const bool writer = active && (ks < 2);     // ks 0,1 write rows 2jj,2jj+1

    __shared__ float h_lds[2][128];
    for (int i = tid; i < 256; i += 256) (&h_lds[0][0])[i] = 0.f;

    // per-lane weights: w2[r][kk] = Whh[dir][2*jj+r][kb+kk], zero for k>=100
    float w2[2][28];
    #pragma unroll
    for (int r = 0; r < 2; ++r) {
        const float* wr = Whh + ((size_t)dir * HID + 2 * jjc + r) * HID + kb;
        #pragma unroll
        for (int q = 0; q < 7; ++q) {
            float4 v = make_float4(0.f, 0.f, 0.f, 0.f);
            if (kb + 4 * q + 3 < HID)   // ks<3: 7 valid; ks==3: 4 valid (k=84..99)
                v = *(const float4*)(wr + 4 * q);
            w2[r][4*q+0] = v.x; w2[r][4*q+1] = v.y;
            w2[r][4*q+2] = v.z; w2[r][4*q+3] = v.w;
        }
    }
    __syncthreads();   // h_lds zero-init visible

    const ptrdiff_t zstride = BATCH * HID;
    const ptrdiff_t ostride = BATCH * 200;
    const int t0 = dir ? (T_LEN - 1) : 0;
    const ptrdiff_t zstep = dir ? -zstride : zstride;
    const ptrdiff_t ostep = dir ? -ostride : ostride;
    const ptrdiff_t zstep2 = 2 * zstep, zstep3 = 3 * zstep, zstep4 = 4 * zstep;

    const float* zp = z + (size_t)dir * M_TOT * HID + (size_t)b * HID + jout
                        + (ptrdiff_t)t0 * zstride;
    float*       op = out + (size_t)b * 200 + dir * HID + jout
                        + (ptrdiff_t)t0 * ostride;

    // 4-deep z prefetch ring (statically indexed named regs)
    float zr0 = zp[0];
    float zr1 = zp[zstep];
    float zr2 = zp[zstep2];
    float zr3 = zp[zstep3];
    const float* zpf = zp + zstep4;

// One step: 7 b128 LDS reads/wave (4 distinct bank-disjoint slices per
// instr, broadcast x16), 56 FMAs vs register weights (two 28-deep chains),
// 2-hop DPP transpose-reduce (lane ks ends with row 2jj+(ks&1) total),
// tanh, ds_write_b32 from ks<2, out store. Raw barrier: lgkmcnt only.
#define RNN_STEP(ZREG, DO_PF, PFOFF, RD, WRB)                           \
  do {                                                                  \
    const float zin = ZREG;                                             \
    if (DO_PF) ZREG = *(zpf + (PFOFF));   /* fire-and-forget prefetch */\
    const float4* hp = (const float4*)((RD) + kb);                      \
    float a0 = 0.f, a1 = 0.f;                                           \
    _Pragma("unroll")                                                   \
    for (int q = 0; q < 7; ++q) {                                       \
      float4 hv = hp[q];                                                \
      a0 += w2[0][4*q+0] * hv.x; a0 += w2[0][4*q+1] * hv.y;             \
      a0 += w2[0][4*q+2] * hv.z; a0 += w2[0][4*q+3] * hv.w;             \
      a1 += w2[1][4*q+0] * hv.x; a1 += w2[1][4*q+1] * hv.y;             \
      a1 += w2[1][4*q+2] * hv.z; a1 += w2[1][4*q+3] * hv.w;             \
    }                                                                   \
    /* hop1 (xor1): lane keeps row (ks&1), receives partner's */        \
    float keep = (ks & 1) ? a1 : a0;                                    \
    float send = (ks & 1) ? a0 : a1;                                    \
    float s = keep + dpp_qxor1(send);                                   \
    /* hop2 (xor2): sum the two slice-pairs -> full 100-k total */      \
    float tot = s + dpp_qxor2(s);                                       \
    float xin = zin + tot;                                              \
    float ax = fabsf(xin);                                              \
    float e = __expf(2.f * ax);                                         \
    float r = 1.f - 2.f / (e + 1.f);                                    \
    float val = copysignf(r, xin);                                      \
    if (writer) {                                                       \
      (WRB)[jout] = val;                                                \
      *op = val;                                                        \
    }                                                                   \
    op += ostep;                                                        \
    asm volatile("s_waitcnt lgkmcnt(0)" ::: "memory");                  \
    __builtin_amdgcn_sched_barrier(0);                                  \
    __builtin_amdgcn_s_barrier();                                       \
    __builtin_amdgcn_sched_barrier(0);                                  \
  } while (0)

    float* const h0 = &h_lds[0][0];
    float* const h1 = &h_lds[1][0];

    // main: 127 groups of 4 steps, prefetching steps s+4..s+7
    for (int g = 0; g < (T_LEN / 4) - 1; ++g) {
        RNN_STEP(zr0, 1, 0,      h0, h1);
        RNN_STEP(zr1, 1, zstep,  h1, h0);
        RNN_STEP(zr2, 1, zstep2, h0, h1);
        RNN_STEP(zr3, 1, zstep3, h1, h0);
        zpf += zstep4;
    }
    // tail: last 4 steps, no prefetch
    RNN_STEP(zr0, 0, 0, h0, h1);
    RNN_STEP(zr1, 0, 0, h1, h0);
    RNN_STEP(zr2, 0, 0, h0, h1);
    RNN_STEP(zr3, 0, 0, h1, h0);

#undef RNN_STEP
}

// ---------------- output projection ----------------
__global__ __launch_bounds__(256) void outproj_kernel(
    const float* __restrict__ h, const float* __restrict__ Wout,
    const float* __restrict__ bout, float* __restrict__ y)
{
    const int gid = blockIdx.x * 256 + threadIdx.x;
    const int wid = gid >> 6;
    const int lane = threadIdx.x & 63;
    if (wid >= M_TOT) return;
    const float* row = h + (size_t)wid * 200;
    float acc = 0.f;
    for (int k = lane; k < 200; k += 64) acc += row[k] * Wout[k];
    #pragma unroll
    for (int off = 32; off > 0; off >>= 1) acc += __shfl_xor(acc, off);
    if (lane == 0) y[wid] = 1.f / (1.f + __expf(-(acc + bout[0])));
}

extern "C" void kernel_launch(void* const* d_in, const int* in_sizes, int n_in,
                              void* d_out, int out_size, void* d_ws, size_t ws_size,
                              hipStream_t stream)
{
    const float* x     = (const float*)d_in[0];
    const float* W_ih0 = (const float*)d_in[1];
    const float* W_ih  = (const float*)d_in[2];
    const float* W_hh  = (const float*)d_in[3];
    const float* b_ih  = (const float*)d_in[4];
    const float* b_hh  = (const float*)d_in[5];
    const float* W_out = (const float*)d_in[6];
    const float* b_out = (const float*)d_in[7];
    float* y = (float*)d_out;

    float* z    = (float*)d_ws;                          // 2*M*100 floats
    float* buf0 = z + (size_t)2 * M_TOT * HID;           // M*200
    float* buf1 = buf0 + (size_t)M_TOT * 200;            // M*200

    for (int l = 0; l < 10; ++l) {
        const float* In = (l == 0) ? x : ((l & 1) ? buf0 : buf1);
        float* Out      = (l & 1) ? buf1 : buf0;
        const int K     = (l == 0) ? 100 : 200;
        const float* W  = (l == 0) ? W_ih0 : (W_ih + (size_t)(l - 1) * 2 * 100 * 200);
        ingemm_kernel<<<dim3(M_TOT / 128, 2), 320, 0, stream>>>(
            In, W, b_ih + l * 200, b_hh + l * 200, z, K);
        scan_kernel<<<128, 256, 0, stream>>>(
            z, W_hh + (size_t)l * 2 * HID * HID, Out);
    }
    outproj_kernel<<<M_TOT / 4, 256, 0, stream>>>(buf1, W_out, b_out, y);
}

// Round 6
// 2204.148 us; speedup vs baseline: 1.0683x; 1.0683x over previous
//
#include <hip/hip_runtime.h>
#include <math.h>

// Bidirectional 10-layer tanh RNN, T=512 B=64 H=100, + sigmoid head.
// Layers strictly sequential (bidir dependency). Per layer:
//   1) ingemm_kernel: z[dir][m][h] = In[m][:] . W[dir*100+h][:] + bias (R4 version)
//   2) scan_kernel:   128 blocks = 2 dirs x 64 batch independent chains
// Final: outproj_kernel (wave-per-row dot200 + sigmoid).
//
// R6: ingemm reverted to R4's proven 64x64 version (R5's "zero-waste" tiling
// regressed 43->58 us/layer). scan: 8-way k-split, 4 ds_read_b128/wave
// (16/step, was 28) with ALL-DPP 3-hop reduction (row_half_mirror 0x141 for
// lane^7 while all 4 row-accs live, then quad xor1/xor2 transpose). Slices:
// base 12*ks width 16 (aligned, banks 12ks+16i cover all 32 exactly once);
// owned k = [12ks+4,12ks+16) for ks>0 -> exact partition of 100. ds_write
// jout=4*slot+q: 32 distinct banks/wave, conflict-free. Raw s_barrier +
// lgkmcnt-only drain + 4-deep z prefetch ring kept.

#define T_LEN 512
#define BATCH 64
#define HID   100
#define M_TOT (T_LEN * BATCH)   // 32768

// ---------------- input GEMM (R4 version, proven 43 us/layer) ----------------
__global__ __launch_bounds__(256) void ingemm_kernel(
    const float* __restrict__ In, const float* __restrict__ W,
    const float* __restrict__ bih, const float* __restrict__ bhh,
    float* __restrict__ z, int K)
{
    __shared__ float As[16][68];
    __shared__ float Bs[16][68];
    const int tid = threadIdx.x;
    const int m0 = blockIdx.x * 64;
    const int n0 = blockIdx.y * 64;
    const int tx = tid & 15, ty = tid >> 4;
    const int lm = tid >> 2;          // 0..63
    const int lk = (tid & 3) << 2;    // 0,4,8,12

    float acc[4][4];
    #pragma unroll
    for (int i = 0; i < 4; ++i)
        #pragma unroll
        for (int j = 0; j < 4; ++j) acc[i][j] = 0.f;

    for (int k0 = 0; k0 < K; k0 += 16) {
        float4 av = make_float4(0.f,0.f,0.f,0.f);
        float4 bv = make_float4(0.f,0.f,0.f,0.f);
        if (k0 + lk < K)   // K%4==0 so a 4-chunk is fully in or out
            av = *(const float4*)(In + (size_t)(m0 + lm) * K + k0 + lk);
        const int nrow = n0 + lm;
        if (nrow < 200 && k0 + lk < K)
            bv = *(const float4*)(W + (size_t)nrow * K + k0 + lk);
        As[lk+0][lm]=av.x; As[lk+1][lm]=av.y; As[lk+2][lm]=av.z; As[lk+3][lm]=av.w;
        Bs[lk+0][lm]=bv.x; Bs[lk+1][lm]=bv.y; Bs[lk+2][lm]=bv.z; Bs[lk+3][lm]=bv.w;
        __syncthreads();
        #pragma unroll
        for (int kk = 0; kk < 16; ++kk) {
            float4 a4 = *(const float4*)&As[kk][ty << 2];
            float4 b4 = *(const float4*)&Bs[kk][tx << 2];
            float a[4] = {a4.x, a4.y, a4.z, a4.w};
            float b[4] = {b4.x, b4.y, b4.z, b4.w};
            #pragma unroll
            for (int i = 0; i < 4; ++i)
                #pragma unroll
                for (int j = 0; j < 4; ++j)
                    acc[i][j] += a[i] * b[j];
        }
        __syncthreads();
    }
    #pragma unroll
    for (int i = 0; i < 4; ++i) {
        const int m = m0 + (ty << 2) + i;
        #pragma unroll
        for (int j = 0; j < 4; ++j) {
            const int n = n0 + (tx << 2) + j;
            if (n < 200) {
                const int dir = (n >= 100) ? 1 : 0;
                const int h = n - dir * 100;
                z[(size_t)dir * M_TOT * HID + (size_t)m * HID + h] =
                    acc[i][j] + bih[n] + bhh[n];
            }
        }
    }
}

// DPP helpers — guaranteed VALU lane exchange (no LDS).
// quad_perm ctrl = p0|p1<<2|p2<<4|p3<<6: xor1 {1,0,3,2}=0xB1, xor2 {2,3,0,1}=0x4E.
// row_half_mirror (lane^7 within groups of 8) = 0x141.
__device__ __forceinline__ float dpp_qxor1(float x) {
    int i = __float_as_int(x);
    i = __builtin_amdgcn_update_dpp(0, i, 0xB1, 0xF, 0xF, false);
    return __int_as_float(i);
}
__device__ __forceinline__ float dpp_qxor2(float x) {
    int i = __float_as_int(x);
    i = __builtin_amdgcn_update_dpp(0, i, 0x4E, 0xF, 0xF, false);
    return __int_as_float(i);
}
__device__ __forceinline__ float dpp_hmir(float x) {  // lane ^ 7
    int i = __float_as_int(x);
    i = __builtin_amdgcn_update_dpp(0, i, 0x141, 0xF, 0xF, false);
    return __int_as_float(i);
}

// ---------------- recurrent scan ----------------
// One block (256 threads, 4 waves) per (dir, batch) chain.
// Lane: q=lane&3, b2=(lane>>2)&1 -> ks = q|(b2<<2) in [0,8);
// slot = (lane>>3) + 8*wave in [0,32), active < 25; rows = 4*slot + r.
// Slice ks reads h[12ks .. 12ks+16); owns k in [12ks+4,12ks+16) (ks>0) or
// [0,16) (ks==0) -> exact partition of [0,100). Reduce over 8 slices:
// hop lane^7 (row_half_mirror, rows preserved since all 4 accs live), then
// quad xor1/xor2 transpose -> lane ends with row q total; writers b2==0.
__global__ __launch_bounds__(256) void scan_kernel(
    const float* __restrict__ z,    // [2][M][HID]
    const float* __restrict__ Whh,  // [2][HID][HID] for this layer
    float* __restrict__ out)        // [M][200]
{
    const int dir = blockIdx.x >> 6;
    const int b   = blockIdx.x & 63;
    const int tid = threadIdx.x;        // 0..255
    const int w   = tid >> 6;           // wave 0..3
    const int lane= tid & 63;
    const int q   = lane & 3;
    const int b2  = (lane >> 2) & 1;
    const int ks  = q | (b2 << 2);      // k-slice 0..7
    const int slot= (lane >> 3) + 8 * w;    // 0..31
    const bool active = (slot < 25);
    const int slotc = active ? slot : 24;
    const int jout = 4 * slotc + q;     // row this lane finalizes (0..99)
    const bool writer = active && (b2 == 0);
    const int kb = 12 * ks;             // slice base (floats); 12*7+16 = 100

    __shared__ float h_lds[2][112];
    for (int i = tid; i < 224; i += 256) (&h_lds[0][0])[i] = 0.f;

    // per-lane weights: w4[r][kk] = Whh[dir][4*slot+r][kb+kk];
    // zero kk<4 for ks>0 (owned-k partition; no double counting).
    float w4[4][16];
    #pragma unroll
    for (int r = 0; r < 4; ++r) {
        const float* wr = Whh + ((size_t)dir * HID + 4 * slotc + r) * HID + kb;
        #pragma unroll
        for (int i = 0; i < 4; ++i) {
            float4 v = *(const float4*)(wr + 4 * i);
            w4[r][4*i+0] = v.x; w4[r][4*i+1] = v.y;
            w4[r][4*i+2] = v.z; w4[r][4*i+3] = v.w;
        }
        if (ks > 0) {
            w4[r][0] = 0.f; w4[r][1] = 0.f; w4[r][2] = 0.f; w4[r][3] = 0.f;
        }
    }
    __syncthreads();   // h_lds zero-init visible

    const ptrdiff_t zstride = BATCH * HID;
    const ptrdiff_t ostride = BATCH * 200;
    const int t0 = dir ? (T_LEN - 1) : 0;
    const ptrdiff_t zstep = dir ? -zstride : zstride;
    const ptrdiff_t ostep = dir ? -ostride : ostride;
    const ptrdiff_t zstep2 = 2 * zstep, zstep3 = 3 * zstep, zstep4 = 4 * zstep;

    const float* zp = z + (size_t)dir * M_TOT * HID + (size_t)b * HID + jout
                        + (ptrdiff_t)t0 * zstride;
    float*       op = out + (size_t)b * 200 + dir * HID + jout
                        + (ptrdiff_t)t0 * ostride;

    // 4-deep z prefetch ring (statically indexed named regs)
    float zr0 = zp[0];
    float zr1 = zp[zstep];
    float zr2 = zp[zstep2];
    float zr3 = zp[zstep3];
    const float* zpf = zp + zstep4;

// One step: 4 b128 LDS reads (8 distinct slices cover all 32 banks once,
// broadcast x8), 64 FMAs vs register weights (4 rows x 16), 3-hop all-DPP
// reduce (lane^7 first while 4 accs live, then quad xor1/xor2 transpose),
// tanh, conflict-free ds_write_b32 from b2==0 lanes. Raw barrier: lgkm only.
#define RNN_STEP(ZREG, DO_PF, PFOFF, RD, WRB)                           \
  do {                                                                  \
    const float zin = ZREG;                                             \
    if (DO_PF) ZREG = *(zpf + (PFOFF));   /* fire-and-forget prefetch */\
    const float4* hp = (const float4*)((RD) + kb);                      \
    float a0 = 0.f, a1 = 0.f, a2 = 0.f, a3 = 0.f;                       \
    _Pragma("unroll")                                                   \
    for (int i = 0; i < 4; ++i) {                                       \
      float4 hv = hp[i];                                                \
      a0 += w4[0][4*i+0] * hv.x; a0 += w4[0][4*i+1] * hv.y;             \
      a0 += w4[0][4*i+2] * hv.z; a0 += w4[0][4*i+3] * hv.w;             \
      a1 += w4[1][4*i+0] * hv.x; a1 += w4[1][4*i+1] * hv.y;             \
      a1 += w4[1][4*i+2] * hv.z; a1 += w4[1][4*i+3] * hv.w;             \
      a2 += w4[2][4*i+0] * hv.x; a2 += w4[2][4*i+1] * hv.y;             \
      a2 += w4[2][4*i+2] * hv.z; a2 += w4[2][4*i+3] * hv.w;             \
      a3 += w4[3][4*i+0] * hv.x; a3 += w4[3][4*i+1] * hv.y;             \
      a3 += w4[3][4*i+2] * hv.z; a3 += w4[3][4*i+3] * hv.w;             \
    }                                                                   \
    /* hop lane^7: rows preserved (all 4 accs), slices s + s^7 */       \
    float t0_ = a0 + dpp_hmir(a0);                                      \
    float t1_ = a1 + dpp_hmir(a1);                                      \
    float t2_ = a2 + dpp_hmir(a2);                                      \
    float t3_ = a3 + dpp_hmir(a3);                                      \
    /* quad xor1: keep rows r&1==q&1 */                                 \
    float k01 = (q & 1) ? t1_ : t0_;                                    \
    float s01s = (q & 1) ? t0_ : t1_;                                   \
    float s01 = k01 + dpp_qxor1(s01s);                                  \
    float k23 = (q & 1) ? t3_ : t2_;                                    \
    float s23s = (q & 1) ? t2_ : t3_;                                   \
    float s23 = k23 + dpp_qxor1(s23s);                                  \
    /* quad xor2: keep rows r&2==q&2 -> row q total over 8 slices */    \
    float kf = (q & 2) ? s23 : s01;                                     \
    float sf = (q & 2) ? s01 : s23;                                     \
    float tot = kf + dpp_qxor2(sf);                                     \
    float xin = zin + tot;                                              \
    float ax = fabsf(xin);                                              \
    float e = __expf(2.f * ax);                                         \
    float r = 1.f - 2.f / (e + 1.f);                                    \
    float val = copysignf(r, xin);                                      \
    if (writer) {                                                       \
      (WRB)[jout] = val;                                                \
      *op = val;                                                        \
    }                                                                   \
    op += ostep;                                                        \
    asm volatile("s_waitcnt lgkmcnt(0)" ::: "memory");                  \
    __builtin_amdgcn_sched_barrier(0);                                  \
    __builtin_amdgcn_s_barrier();                                       \
    __builtin_amdgcn_sched_barrier(0);                                  \
  } while (0)

    float* const h0 = &h_lds[0][0];
    float* const h1 = &h_lds[1][0];

    // main: 127 groups of 4 steps, prefetching steps s+4..s+7
    for (int g = 0; g < (T_LEN / 4) - 1; ++g) {
        RNN_STEP(zr0, 1, 0,      h0, h1);
        RNN_STEP(zr1, 1, zstep,  h1, h0);
        RNN_STEP(zr2, 1, zstep2, h0, h1);
        RNN_STEP(zr3, 1, zstep3, h1, h0);
        zpf += zstep4;
    }
    // tail: last 4 steps, no prefetch
    RNN_STEP(zr0, 0, 0, h0, h1);
    RNN_STEP(zr1, 0, 0, h1, h0);
    RNN_STEP(zr2, 0, 0, h0, h1);
    RNN_STEP(zr3, 0, 0, h1, h0);

#undef RNN_STEP
}

// ---------------- output projection ----------------
__global__ __launch_bounds__(256) void outproj_kernel(
    const float* __restrict__ h, const float* __restrict__ Wout,
    const float* __restrict__ bout, float* __restrict__ y)
{
    const int gid = blockIdx.x * 256 + threadIdx.x;
    const int wid = gid >> 6;
    const int lane = threadIdx.x & 63;
    if (wid >= M_TOT) return;
    const float* row = h + (size_t)wid * 200;
    float acc = 0.f;
    for (int k = lane; k < 200; k += 64) acc += row[k] * Wout[k];
    #pragma unroll
    for (int off = 32; off > 0; off >>= 1) acc += __shfl_xor(acc, off);
    if (lane == 0) y[wid] = 1.f / (1.f + __expf(-(acc + bout[0])));
}

extern "C" void kernel_launch(void* const* d_in, const int* in_sizes, int n_in,
                              void* d_out, int out_size, void* d_ws, size_t ws_size,
                              hipStream_t stream)
{
    const float* x     = (const float*)d_in[0];
    const float* W_ih0 = (const float*)d_in[1];
    const float* W_ih  = (const float*)d_in[2];
    const float* W_hh  = (const float*)d_in[3];
    const float* b_ih  = (const float*)d_in[4];
    const float* b_hh  = (const float*)d_in[5];
    const float* W_out = (const float*)d_in[6];
    const float* b_out = (const float*)d_in[7];
    float* y = (float*)d_out;

    float* z    = (float*)d_ws;                          // 2*M*100 floats
    float* buf0 = z + (size_t)2 * M_TOT * HID;           // M*200
    float* buf1 = buf0 + (size_t)M_TOT * 200;            // M*200

    for (int l = 0; l < 10; ++l) {
        const float* In = (l == 0) ? x : ((l & 1) ? buf0 : buf1);
        float* Out      = (l & 1) ? buf1 : buf0;
        const int K     = (l == 0) ? 100 : 200;
        const float* W  = (l == 0) ? W_ih0 : (W_ih + (size_t)(l - 1) * 2 * 100 * 200);
        ingemm_kernel<<<dim3(M_TOT / 64, 4), 256, 0, stream>>>(
            In, W, b_ih + l * 200, b_hh + l * 200, z, K);
        scan_kernel<<<128, 256, 0, stream>>>(
            z, W_hh + (size_t)l * 2 * HID * HID, Out);
    }
    outproj_kernel<<<M_TOT / 4, 256, 0, stream>>>(buf1, W_out, b_out, y);
}

// Round 7
// 2204.040 us; speedup vs baseline: 1.0683x; 1.0000x over previous
//
#include <hip/hip_runtime.h>
#include <math.h>

// Bidirectional 10-layer tanh RNN, T=512 B=64 H=100, + sigmoid head.
// Layers strictly sequential (bidir dependency). Per layer:
//   1) ingemm_kernel: z[dir][m][h] = In[m][:] . W[dir*100+h][:] + bias
//   2) scan_kernel:   128 blocks = 2 dirs x 64 batch independent chains
// Final: outproj_kernel (wave-per-row dot200 + sigmoid).
//
// R7: scan banked at its turnaround floor (R6 == R4 at 173.6us despite
// -12 DS instrs and 0 conflicts -> barrier+exchange dominated, structural).
// ingemm M-tile 64 -> 128 (acc 8x4): per kk 3 b128 reads -> 32 FMAs
// (ratio 8->10.7), staging/guards byte-identical pattern to the proven R4
// kernel (A staged in two 64-row reps), barriers per FLOP halved.

#define T_LEN 512
#define BATCH 64
#define HID   100
#define M_TOT (T_LEN * BATCH)   // 32768

// ---------------- input GEMM (128x64 tile, R4 staging pattern) ----------------
// Grid: (M_TOT/128, 4). Block 256: tx = tid&15 (4 cols), ty = tid>>4
// (8 rows: ty*4..+3 and 64+ty*4..+3).
__global__ __launch_bounds__(256) void ingemm_kernel(
    const float* __restrict__ In, const float* __restrict__ W,
    const float* __restrict__ bih, const float* __restrict__ bhh,
    float* __restrict__ z, int K)
{
    __shared__ float As[16][132];   // [k][m], 128 rows + pad
    __shared__ float Bs[16][68];    // [k][n], 64 cols + pad
    const int tid = threadIdx.x;
    const int m0 = blockIdx.x * 128;
    const int n0 = blockIdx.y * 64;
    const int tx = tid & 15, ty = tid >> 4;
    const int lm = tid >> 2;          // 0..63
    const int lk = (tid & 3) << 2;    // 0,4,8,12

    float acc[8][4];
    #pragma unroll
    for (int i = 0; i < 8; ++i)
        #pragma unroll
        for (int j = 0; j < 4; ++j) acc[i][j] = 0.f;

    for (int k0 = 0; k0 < K; k0 += 16) {
        // stage A: 128 rows x 16 k, two 64-row reps of the proven pattern
        #pragma unroll
        for (int rep = 0; rep < 2; ++rep) {
            float4 av = make_float4(0.f,0.f,0.f,0.f);
            const int row = lm + 64 * rep;
            if (k0 + lk < K)   // K%4==0 so a 4-chunk is fully in or out
                av = *(const float4*)(In + (size_t)(m0 + row) * K + k0 + lk);
            As[lk+0][row]=av.x; As[lk+1][row]=av.y;
            As[lk+2][row]=av.z; As[lk+3][row]=av.w;
        }
        // stage B: 64 cols x 16 k (identical to R4)
        {
            float4 bv = make_float4(0.f,0.f,0.f,0.f);
            const int nrow = n0 + lm;
            if (nrow < 200 && k0 + lk < K)
                bv = *(const float4*)(W + (size_t)nrow * K + k0 + lk);
            Bs[lk+0][lm]=bv.x; Bs[lk+1][lm]=bv.y;
            Bs[lk+2][lm]=bv.z; Bs[lk+3][lm]=bv.w;
        }
        __syncthreads();
        #pragma unroll
        for (int kk = 0; kk < 16; ++kk) {
            float4 alo = *(const float4*)&As[kk][ty << 2];
            float4 ahi = *(const float4*)&As[kk][64 + (ty << 2)];
            float4 b4  = *(const float4*)&Bs[kk][tx << 2];
            float a[8] = {alo.x, alo.y, alo.z, alo.w,
                          ahi.x, ahi.y, ahi.z, ahi.w};
            float b[4] = {b4.x, b4.y, b4.z, b4.w};
            #pragma unroll
            for (int i = 0; i < 8; ++i)
                #pragma unroll
                for (int j = 0; j < 4; ++j)
                    acc[i][j] += a[i] * b[j];
        }
        __syncthreads();
    }
    #pragma unroll
    for (int i = 0; i < 8; ++i) {
        const int m = m0 + ((i < 4) ? ((ty << 2) + i) : (64 + (ty << 2) + (i - 4)));
        #pragma unroll
        for (int j = 0; j < 4; ++j) {
            const int n = n0 + (tx << 2) + j;
            if (n < 200) {
                const int dir = (n >= 100) ? 1 : 0;
                const int h = n - dir * 100;
                z[(size_t)dir * M_TOT * HID + (size_t)m * HID + h] =
                    acc[i][j] + bih[n] + bhh[n];
            }
        }
    }
}

// DPP helpers — guaranteed VALU lane exchange (no LDS).
// quad_perm ctrl = p0|p1<<2|p2<<4|p3<<6: xor1 {1,0,3,2}=0xB1, xor2 {2,3,0,1}=0x4E.
// row_half_mirror (lane^7 within groups of 8) = 0x141.
__device__ __forceinline__ float dpp_qxor1(float x) {
    int i = __float_as_int(x);
    i = __builtin_amdgcn_update_dpp(0, i, 0xB1, 0xF, 0xF, false);
    return __int_as_float(i);
}
__device__ __forceinline__ float dpp_qxor2(float x) {
    int i = __float_as_int(x);
    i = __builtin_amdgcn_update_dpp(0, i, 0x4E, 0xF, 0xF, false);
    return __int_as_float(i);
}
__device__ __forceinline__ float dpp_hmir(float x) {  // lane ^ 7
    int i = __float_as_int(x);
    i = __builtin_amdgcn_update_dpp(0, i, 0x141, 0xF, 0xF, false);
    return __int_as_float(i);
}

// ---------------- recurrent scan (R6, banked at turnaround floor) ----------------
// One block (256 threads, 4 waves) per (dir, batch) chain.
// Lane: q=lane&3, b2=(lane>>2)&1 -> ks = q|(b2<<2) in [0,8);
// slot = (lane>>3) + 8*wave in [0,32), active < 25; rows = 4*slot + r.
// Slice ks reads h[12ks .. 12ks+16); owns k in [12ks+4,12ks+16) (ks>0) or
// [0,16) (ks==0) -> exact partition of [0,100). Reduce over 8 slices:
// hop lane^7 (row_half_mirror, rows preserved since all 4 accs live), then
// quad xor1/xor2 transpose -> lane ends with row q total; writers b2==0.
__global__ __launch_bounds__(256) void scan_kernel(
    const float* __restrict__ z,    // [2][M][HID]
    const float* __restrict__ Whh,  // [2][HID][HID] for this layer
    float* __restrict__ out)        // [M][200]
{
    const int dir = blockIdx.x >> 6;
    const int b   = blockIdx.x & 63;
    const int tid = threadIdx.x;        // 0..255
    const int w   = tid >> 6;           // wave 0..3
    const int lane= tid & 63;
    const int q   = lane & 3;
    const int b2  = (lane >> 2) & 1;
    const int ks  = q | (b2 << 2);      // k-slice 0..7
    const int slot= (lane >> 3) + 8 * w;    // 0..31
    const bool active = (slot < 25);
    const int slotc = active ? slot : 24;
    const int jout = 4 * slotc + q;     // row this lane finalizes (0..99)
    const bool writer = active && (b2 == 0);
    const int kb = 12 * ks;             // slice base (floats); 12*7+16 = 100

    __shared__ float h_lds[2][112];
    for (int i = tid; i < 224; i += 256) (&h_lds[0][0])[i] = 0.f;

    // per-lane weights: w4[r][kk] = Whh[dir][4*slot+r][kb+kk];
    // zero kk<4 for ks>0 (owned-k partition; no double counting).
    float w4[4][16];
    #pragma unroll
    for (int r = 0; r < 4; ++r) {
        const float* wr = Whh + ((size_t)dir * HID + 4 * slotc + r) * HID + kb;
        #pragma unroll
        for (int i = 0; i < 4; ++i) {
            float4 v = *(const float4*)(wr + 4 * i);
            w4[r][4*i+0] = v.x; w4[r][4*i+1] = v.y;
            w4[r][4*i+2] = v.z; w4[r][4*i+3] = v.w;
        }
        if (ks > 0) {
            w4[r][0] = 0.f; w4[r][1] = 0.f; w4[r][2] = 0.f; w4[r][3] = 0.f;
        }
    }
    __syncthreads();   // h_lds zero-init visible

    const ptrdiff_t zstride = BATCH * HID;
    const ptrdiff_t ostride = BATCH * 200;
    const int t0 = dir ? (T_LEN - 1) : 0;
    const ptrdiff_t zstep = dir ? -zstride : zstride;
    const ptrdiff_t ostep = dir ? -ostride : ostride;
    const ptrdiff_t zstep2 = 2 * zstep, zstep3 = 3 * zstep, zstep4 = 4 * zstep;

    const float* zp = z + (size_t)dir * M_TOT * HID + (size_t)b * HID + jout
                        + (ptrdiff_t)t0 * zstride;
    float*       op = out + (size_t)b * 200 + dir * HID + jout
                        + (ptrdiff_t)t0 * ostride;

    // 4-deep z prefetch ring (statically indexed named regs)
    float zr0 = zp[0];
    float zr1 = zp[zstep];
    float zr2 = zp[zstep2];
    float zr3 = zp[zstep3];
    const float* zpf = zp + zstep4;

// One step: 4 b128 LDS reads (8 distinct slices cover all 32 banks once,
// broadcast x8), 64 FMAs vs register weights (4 rows x 16), 3-hop all-DPP
// reduce (lane^7 first while 4 accs live, then quad xor1/xor2 transpose),
// tanh, conflict-free ds_write_b32 from b2==0 lanes. Raw barrier: lgkm only.
#define RNN_STEP(ZREG, DO_PF, PFOFF, RD, WRB)                           \
  do {                                                                  \
    const float zin = ZREG;                                             \
    if (DO_PF) ZREG = *(zpf + (PFOFF));   /* fire-and-forget prefetch */\
    const float4* hp = (const float4*)((RD) + kb);                      \
    float a0 = 0.f, a1 = 0.f, a2 = 0.f, a3 = 0.f;                       \
    _Pragma("unroll")                                                   \
    for (int i = 0; i < 4; ++i) {                                       \
      float4 hv = hp[i];                                                \
      a0 += w4[0][4*i+0] * hv.x; a0 += w4[0][4*i+1] * hv.y;             \
      a0 += w4[0][4*i+2] * hv.z; a0 += w4[0][4*i+3] * hv.w;             \
      a1 += w4[1][4*i+0] * hv.x; a1 += w4[1][4*i+1] * hv.y;             \
      a1 += w4[1][4*i+2] * hv.z; a1 += w4[1][4*i+3] * hv.w;             \
      a2 += w4[2][4*i+0] * hv.x; a2 += w4[2][4*i+1] * hv.y;             \
      a2 += w4[2][4*i+2] * hv.z; a2 += w4[2][4*i+3] * hv.w;             \
      a3 += w4[3][4*i+0] * hv.x; a3 += w4[3][4*i+1] * hv.y;             \
      a3 += w4[3][4*i+2] * hv.z; a3 += w4[3][4*i+3] * hv.w;             \
    }                                                                   \
    /* hop lane^7: rows preserved (all 4 accs), slices s + s^7 */       \
    float t0_ = a0 + dpp_hmir(a0);                                      \
    float t1_ = a1 + dpp_hmir(a1);                                      \
    float t2_ = a2 + dpp_hmir(a2);                                      \
    float t3_ = a3 + dpp_hmir(a3);                                      \
    /* quad xor1: keep rows r&1==q&1 */                                 \
    float k01 = (q & 1) ? t1_ : t0_;                                    \
    float s01s = (q & 1) ? t0_ : t1_;                                   \
    float s01 = k01 + dpp_qxor1(s01s);                                  \
    float k23 = (q & 1) ? t3_ : t2_;                                    \
    float s23s = (q & 1) ? t2_ : t3_;                                   \
    float s23 = k23 + dpp_qxor1(s23s);                                  \
    /* quad xor2: keep rows r&2==q&2 -> row q total over 8 slices */    \
    float kf = (q & 2) ? s23 : s01;                                     \
    float sf = (q & 2) ? s01 : s23;                                     \
    float tot = kf + dpp_qxor2(sf);                                     \
    float xin = zin + tot;                                              \
    float ax = fabsf(xin);                                              \
    float e = __expf(2.f * ax);                                         \
    float r = 1.f - 2.f / (e + 1.f);                                    \
    float val = copysignf(r, xin);                                      \
    if (writer) {                                                       \
      (WRB)[jout] = val;                                                \
      *op = val;                                                        \
    }                                                                   \
    op += ostep;                                                        \
    asm volatile("s_waitcnt lgkmcnt(0)" ::: "memory");                  \
    __builtin_amdgcn_sched_barrier(0);                                  \
    __builtin_amdgcn_s_barrier();                                       \
    __builtin_amdgcn_sched_barrier(0);                                  \
  } while (0)

    float* const h0 = &h_lds[0][0];
    float* const h1 = &h_lds[1][0];

    // main: 127 groups of 4 steps, prefetching steps s+4..s+7
    for (int g = 0; g < (T_LEN / 4) - 1; ++g) {
        RNN_STEP(zr0, 1, 0,      h0, h1);
        RNN_STEP(zr1, 1, zstep,  h1, h0);
        RNN_STEP(zr2, 1, zstep2, h0, h1);
        RNN_STEP(zr3, 1, zstep3, h1, h0);
        zpf += zstep4;
    }
    // tail: last 4 steps, no prefetch
    RNN_STEP(zr0, 0, 0, h0, h1);
    RNN_STEP(zr1, 0, 0, h1, h0);
    RNN_STEP(zr2, 0, 0, h0, h1);
    RNN_STEP(zr3, 0, 0, h1, h0);

#undef RNN_STEP
}

// ---------------- output projection ----------------
__global__ __launch_bounds__(256) void outproj_kernel(
    const float* __restrict__ h, const float* __restrict__ Wout,
    const float* __restrict__ bout, float* __restrict__ y)
{
    const int gid = blockIdx.x * 256 + threadIdx.x;
    const int wid = gid >> 6;
    const int lane = threadIdx.x & 63;
    if (wid >= M_TOT) return;
    const float* row = h + (size_t)wid * 200;
    float acc = 0.f;
    for (int k = lane; k < 200; k += 64) acc += row[k] * Wout[k];
    #pragma unroll
    for (int off = 32; off > 0; off >>= 1) acc += __shfl_xor(acc, off);
    if (lane == 0) y[wid] = 1.f / (1.f + __expf(-(acc + bout[0])));
}

extern "C" void kernel_launch(void* const* d_in, const int* in_sizes, int n_in,
                              void* d_out, int out_size, void* d_ws, size_t ws_size,
                              hipStream_t stream)
{
    const float* x     = (const float*)d_in[0];
    const float* W_ih0 = (const float*)d_in[1];
    const float* W_ih  = (const float*)d_in[2];
    const float* W_hh  = (const float*)d_in[3];
    const float* b_ih  = (const float*)d_in[4];
    const float* b_hh  = (const float*)d_in[5];
    const float* W_out = (const float*)d_in[6];
    const float* b_out = (const float*)d_in[7];
    float* y = (float*)d_out;

    float* z    = (float*)d_ws;                          // 2*M*100 floats
    float* buf0 = z + (size_t)2 * M_TOT * HID;           // M*200
    float* buf1 = buf0 + (size_t)M_TOT * 200;            // M*200

    for (int l = 0; l < 10; ++l) {
        const float* In = (l == 0) ? x : ((l & 1) ? buf0 : buf1);
        float* Out      = (l & 1) ? buf1 : buf0;
        const int K     = (l == 0) ? 100 : 200;
        const float* W  = (l == 0) ? W_ih0 : (W_ih + (size_t)(l - 1) * 2 * 100 * 200);
        ingemm_kernel<<<dim3(M_TOT / 128, 4), 256, 0, stream>>>(
            In, W, b_ih + l * 200, b_hh + l * 200, z, K);
        scan_kernel<<<128, 256, 0, stream>>>(
            z, W_hh + (size_t)l * 2 * HID * HID, Out);
    }
    outproj_kernel<<<M_TOT / 4, 256, 0, stream>>>(buf1, W_out, b_out, y);
}